// Round 7
// baseline (504.452 us; speedup 1.0000x reference)
//
#include <hip/hip_runtime.h>

#define BB 512
#define TT 512
#define NTAG 64

typedef float f32x4 __attribute__((ext_vector_type(4)));

// Broadcast lane l's value of v to all lanes via v_readlane (SGPR dest).
#define BCAST(v, l) __uint_as_float((unsigned)__builtin_amdgcn_readlane((int)__float_as_uint(v), (l)))

// 16 float4 register buffers (64 floats) — written ONLY by asm ds_read_b128.
#define DECLB(P) \
    f32x4 P##0 = {0,0,0,0}, P##1 = {0,0,0,0}, P##2 = {0,0,0,0}, P##3 = {0,0,0,0}, \
          P##4 = {0,0,0,0}, P##5 = {0,0,0,0}, P##6 = {0,0,0,0}, P##7 = {0,0,0,0}, \
          P##8 = {0,0,0,0}, P##9 = {0,0,0,0}, P##10 = {0,0,0,0}, P##11 = {0,0,0,0}, \
          P##12 = {0,0,0,0}, P##13 = {0,0,0,0}, P##14 = {0,0,0,0}, P##15 = {0,0,0,0};

// 8x ds_read_b128 of one half-row of E_lds (lane j's row, stride 65 floats:
// +1-pad makes consecutive lanes start on consecutive banks -> conflict-free).
// asm volatile + "memory": cannot be hoisted/remat'd/DCE'd; keeps the E-bake
// ds_writes alive and ordered before the first read.
#define READ_LO(P) \
    asm volatile( \
        "ds_read_b128 %0, %8 offset:0\n\t" \
        "ds_read_b128 %1, %8 offset:16\n\t" \
        "ds_read_b128 %2, %8 offset:32\n\t" \
        "ds_read_b128 %3, %8 offset:48\n\t" \
        "ds_read_b128 %4, %8 offset:64\n\t" \
        "ds_read_b128 %5, %8 offset:80\n\t" \
        "ds_read_b128 %6, %8 offset:96\n\t" \
        "ds_read_b128 %7, %8 offset:112" \
        : "=&v"(P##0), "=&v"(P##1), "=&v"(P##2), "=&v"(P##3), \
          "=&v"(P##4), "=&v"(P##5), "=&v"(P##6), "=&v"(P##7) \
        : "v"(vaddr) : "memory");

#define READ_HI(P) \
    asm volatile( \
        "ds_read_b128 %0, %8 offset:128\n\t" \
        "ds_read_b128 %1, %8 offset:144\n\t" \
        "ds_read_b128 %2, %8 offset:160\n\t" \
        "ds_read_b128 %3, %8 offset:176\n\t" \
        "ds_read_b128 %4, %8 offset:192\n\t" \
        "ds_read_b128 %5, %8 offset:208\n\t" \
        "ds_read_b128 %6, %8 offset:224\n\t" \
        "ds_read_b128 %7, %8 offset:240" \
        : "=&v"(P##8), "=&v"(P##9), "=&v"(P##10), "=&v"(P##11), \
          "=&v"(P##12), "=&v"(P##13), "=&v"(P##14), "=&v"(P##15) \
        : "v"(vaddr) : "memory");

// One 16-wide sub-matvec: acc += x_c[j^h^q] * e[h+q], h in {0,4,8,12} via
// mov_dpp bases (row_half_mirror=xor7, row_mirror=xor15, quad_perm[3,2,1,0]
// =xor3 - all involutions, direction-proof), q in {0..3} fused into
// v_fmac_f32_dpp quad_perm (also involutions). s_nop 1 covers VALU->DPP
// wait states.
#define PHASE(XC, E0, E1, E2, E3) \
    asm volatile( \
        "s_nop 1\n\t" \
        "v_mov_b32_dpp %[t7], %[xc] row_half_mirror row_mask:0xf bank_mask:0xf\n\t" \
        "v_mov_b32_dpp %[tf], %[xc] row_mirror row_mask:0xf bank_mask:0xf\n\t" \
        "s_nop 1\n\t" \
        "v_mov_b32_dpp %[b4], %[t7] quad_perm:[3,2,1,0] row_mask:0xf bank_mask:0xf\n\t" \
        "v_mov_b32_dpp %[b8], %[tf] row_half_mirror row_mask:0xf bank_mask:0xf\n\t" \
        "v_mov_b32_dpp %[bc], %[tf] quad_perm:[3,2,1,0] row_mask:0xf bank_mask:0xf\n\t" \
        "s_nop 1\n\t" \
        "v_fmac_f32 %[a0], %[xc], %[e0]\n\t" \
        "v_fmac_f32_dpp %[a1], %[xc], %[e1] quad_perm:[1,0,3,2] row_mask:0xf bank_mask:0xf\n\t" \
        "v_fmac_f32_dpp %[a2], %[xc], %[e2] quad_perm:[2,3,0,1] row_mask:0xf bank_mask:0xf\n\t" \
        "v_fmac_f32_dpp %[a3], %[xc], %[e3] quad_perm:[3,2,1,0] row_mask:0xf bank_mask:0xf\n\t" \
        "v_fmac_f32 %[a0], %[b4], %[e4]\n\t" \
        "v_fmac_f32_dpp %[a1], %[b4], %[e5] quad_perm:[1,0,3,2] row_mask:0xf bank_mask:0xf\n\t" \
        "v_fmac_f32_dpp %[a2], %[b4], %[e6] quad_perm:[2,3,0,1] row_mask:0xf bank_mask:0xf\n\t" \
        "v_fmac_f32_dpp %[a3], %[b4], %[e7] quad_perm:[3,2,1,0] row_mask:0xf bank_mask:0xf\n\t" \
        "v_fmac_f32 %[a0], %[b8], %[e8]\n\t" \
        "v_fmac_f32_dpp %[a1], %[b8], %[e9] quad_perm:[1,0,3,2] row_mask:0xf bank_mask:0xf\n\t" \
        "v_fmac_f32_dpp %[a2], %[b8], %[e10] quad_perm:[2,3,0,1] row_mask:0xf bank_mask:0xf\n\t" \
        "v_fmac_f32_dpp %[a3], %[b8], %[e11] quad_perm:[3,2,1,0] row_mask:0xf bank_mask:0xf\n\t" \
        "v_fmac_f32 %[a0], %[bc], %[e12]\n\t" \
        "v_fmac_f32_dpp %[a1], %[bc], %[e13] quad_perm:[1,0,3,2] row_mask:0xf bank_mask:0xf\n\t" \
        "v_fmac_f32_dpp %[a2], %[bc], %[e14] quad_perm:[2,3,0,1] row_mask:0xf bank_mask:0xf\n\t" \
        "v_fmac_f32_dpp %[a3], %[bc], %[e15] quad_perm:[3,2,1,0] row_mask:0xf bank_mask:0xf" \
        : [a0]"+v"(sA), [a1]"+v"(sB), [a2]"+v"(sC_), [a3]"+v"(sD), \
          [t7]"=&v"(ph_t7), [tf]"=&v"(ph_tf), [b4]"=&v"(ph_b4), \
          [b8]"=&v"(ph_b8), [bc]"=&v"(ph_bc) \
        : [xc]"v"(XC), \
          [e0]"v"((E0).x), [e1]"v"((E0).y), [e2]"v"((E0).z), [e3]"v"((E0).w), \
          [e4]"v"((E1).x), [e5]"v"((E1).y), [e6]"v"((E1).z), [e7]"v"((E1).w), \
          [e8]"v"((E2).x), [e9]"v"((E2).y), [e10]"v"((E2).z), [e11]"v"((E2).w), \
          [e12]"v"((E3).x), [e13]"v"((E3).y), [e14]"v"((E3).z), [e15]"v"((E3).w));

// One recurrence step. Q = this step's E regs (read last step), R = prefetch
// target. All lgkmcnt counts are FIFO-guarantees (DS completes in order per
// wave), not timing assumptions.
#define STEP(Q, R, T) { \
    const float cur = pre0; pre0 = pre1; pre1 = pre2; \
    pre2 = emit[(size_t)min((T) + 3, last) * NTAG + j]; \
    const float C = BCAST(alpha, 0); \
    const float x = __expf(alpha - C); \
    float x1, x2, x3; \
    float ph_t7, ph_tf, ph_b4, ph_b8, ph_bc; \
    asm volatile("ds_swizzle_b32 %0, %2 offset:0x401f\n\t" \
                 "ds_bpermute_b32 %1, %3, %2" \
                 : "=&v"(x1), "=&v"(x2) : "v"(x), "v"(va32)); \
    float sA = 0.f, sB = 0.f, sC_ = 0.f, sD = 0.f; \
    /* entry FIFO: Q(<=16) + swz + bperm = <=18; <=10 left => Q0..Q7 done */ \
    asm volatile("s_waitcnt lgkmcnt(10)" \
                 : "+v"(Q##0), "+v"(Q##1), "+v"(Q##2), "+v"(Q##3)); \
    PHASE(x, Q##0, Q##1, Q##2, Q##3) \
    asm volatile("s_waitcnt lgkmcnt(0)" \
                 : "+v"(x1), "+v"(x2), \
                   "+v"(Q##4), "+v"(Q##5), "+v"(Q##6), "+v"(Q##7), \
                   "+v"(Q##8), "+v"(Q##9), "+v"(Q##10), "+v"(Q##11), \
                   "+v"(Q##12), "+v"(Q##13), "+v"(Q##14), "+v"(Q##15)); \
    asm volatile("ds_bpermute_b32 %0, %1, %2" \
                 : "=&v"(x3) : "v"(va32), "v"(x1)); \
    READ_LO(R) \
    PHASE(x1, Q##4, Q##5, Q##6, Q##7) \
    PHASE(x2, Q##8, Q##9, Q##10, Q##11) \
    READ_HI(R) \
    /* FIFO: [bp3, R0-7(8), R8-15(8)]; <=8 left => bp3 and R0-7 done */ \
    asm volatile("s_waitcnt lgkmcnt(8)" : "+v"(x3)); \
    PHASE(x3, Q##12, Q##13, Q##14, Q##15) \
    const float s = (sA + sB) + (sC_ + sD); \
    alpha = cur + C + __logf(s); \
}

__global__ __launch_bounds__(64, 1) void crf_kernel(
    const float* __restrict__ inputs,   // [B,T,N] f32
    const float* __restrict__ trans,    // [N,N]   f32
    const int*   __restrict__ tags,     // [B,T]   i32
    const int*   __restrict__ lens,     // [B]     i32
    float*       __restrict__ out)      // [B]     f32 (log_likelihood)
{
    __shared__ float E_lds[NTAG * 65];  // lane j's row at j*65, +1 pad

    const int b = blockIdx.x;
    const int j = threadIdx.x;           // 0..63
    const int len  = lens[b];
    const int last = (len - 1) > 0 ? (len - 1) : 0;

    // ---------------- sequence score (gathers) ----------------
    float sc = 0.f;
    #pragma unroll
    for (int tt = 0; tt < TT / 64; ++tt) {
        const int t = tt * 64 + j;
        if (t < len) {
            const int tg = tags[b * TT + t];
            sc += inputs[(size_t)b * TT * NTAG + (size_t)t * NTAG + tg];
            if (t >= 1) {
                const int tp = tags[b * TT + t - 1];
                sc += trans[tp * NTAG + tg];
            }
        }
    }
    #pragma unroll
    for (int m = 32; m >= 1; m >>= 1) sc += __shfl_xor(sc, m);

    // ---------------- bake E into LDS ----------------
    // Slot idx = (16c | h | q) decomposition; term at lane j, slot idx is
    // x[j^idx] * E[j^idx][j], so bake E_lds[j][idx] = exp(trans[(j^idx)*64+j]).
    #pragma unroll 8
    for (int idx = 0; idx < NTAG; ++idx) {
        const int i = j ^ idx;
        E_lds[j * 65 + idx] = __expf(trans[i * NTAG + j]);
    }

    // force sc's cross-lane reduce (and its DS waits) to retire pre-loop,
    // so in-loop lgkmcnt counting sees only our own DS ops.
    asm volatile("" : "+v"(sc));

    const unsigned vaddr = (unsigned)(uintptr_t)(&E_lds[j * 65]);
    const unsigned va32  = (unsigned)((j ^ 32) * 4);   // ds_bpermute: lane = addr>>2

    // ---------------- forward recurrence ----------------
    const float* emit = inputs + (size_t)b * TT * NTAG;
    float alpha = emit[j];

    float pre0 = emit[(size_t)min(1, last) * NTAG + j];
    float pre1 = emit[(size_t)min(2, last) * NTAG + j];
    float pre2 = emit[(size_t)min(3, last) * NTAG + j];

    DECLB(Qv)
    DECLB(Rv)
    READ_LO(Qv)
    READ_HI(Qv)

    int t = 1;
    for (; t + 1 <= last; t += 2) {
        STEP(Qv, Rv, t)
        STEP(Rv, Qv, t + 1)
    }
    if (t <= last) STEP(Qv, Rv, t)

    // final logsumexp over lanes (exact max — runs once)
    float C2 = alpha;
    #pragma unroll
    for (int m = 32; m >= 1; m >>= 1) C2 = fmaxf(C2, __shfl_xor(C2, m));
    float xs = __expf(alpha - C2);
    #pragma unroll
    for (int m = 32; m >= 1; m >>= 1) xs += __shfl_xor(xs, m);
    const float lognorm = C2 + __logf(xs);

    if (j == 0) out[b] = sc - lognorm;
}

__global__ __launch_bounds__(256) void copy_trans_kernel(
    const float* __restrict__ trans, float* __restrict__ out)
{
    const int k = blockIdx.x * 256 + threadIdx.x;
    if (k < NTAG * NTAG) out[k] = trans[k];
}

extern "C" void kernel_launch(void* const* d_in, const int* in_sizes, int n_in,
                              void* d_out, int out_size, void* d_ws, size_t ws_size,
                              hipStream_t stream) {
    const float* inputs = (const float*)d_in[0];
    const float* trans  = (const float*)d_in[1];
    const int*   tags   = (const int*)d_in[2];
    const int*   lens   = (const int*)d_in[3];
    float* out = (float*)d_out;

    crf_kernel<<<BB, 64, 0, stream>>>(inputs, trans, tags, lens, out);
    copy_trans_kernel<<<(NTAG * NTAG + 255) / 256, 256, 0, stream>>>(trans, out + BB);
}

// Round 8
// 271.999 us; speedup vs baseline: 1.8546x; 1.8546x over previous
//
#include <hip/hip_runtime.h>

#define BB 512
#define TT 512
#define NTAG 64

// Broadcast lane `l`'s value of v to all lanes via v_readlane (SGPR dest).
#define BCAST(v, l) __uint_as_float((unsigned)__builtin_amdgcn_readlane((int)__float_as_uint(v), (l)))

#define DECL4(a,b,c,d) \
    float e##a = __expf(trans[a * NTAG + j]); \
    float e##b = __expf(trans[b * NTAG + j]); \
    float e##c = __expf(trans[c * NTAG + j]); \
    float e##d = __expf(trans[d * NTAG + j]);

#define FMA4(a,b,c,d) \
    sA = fmaf(BCAST(x, a), e##a, sA); \
    sB = fmaf(BCAST(x, b), e##b, sB); \
    sC = fmaf(BCAST(x, c), e##c, sC); \
    sD = fmaf(BCAST(x, d), e##d, sD);

// amdgpu_waves_per_eu(1,1): sets MIN AND MAX waves/EU to 1, giving the
// register allocator the full 512-VGPR budget. __launch_bounds__(64,1) only
// sets the minimum, so the allocator kept targeting ~8 waves/EU (~64-reg
// budget) and spilled/remat'd the 64 E-values into the loop on every round
// R3-R7 (VGPR_Count 44-68, ~1000 cyc/step on reload latency). We only ever
// run 2 waves/CU (512 one-wave blocks on 256 CUs), so capping occupancy at
// 4 waves/CU costs nothing.
__global__ __attribute__((amdgpu_waves_per_eu(1, 1))) __launch_bounds__(64)
void crf_kernel(
    const float* __restrict__ inputs,   // [B,T,N] f32
    const float* __restrict__ trans,    // [N,N]   f32
    const int*   __restrict__ tags,     // [B,T]   i32
    const int*   __restrict__ lens,     // [B]     i32
    float*       __restrict__ out)      // [B]     f32 (log_likelihood)
{
    const int b = blockIdx.x;
    const int j = threadIdx.x;           // 0..63
    const int len  = lens[b];
    const int last = (len - 1) > 0 ? (len - 1) : 0;

    // ---------------- sequence score (gathers) ----------------
    float sc = 0.f;
    #pragma unroll
    for (int tt = 0; tt < TT / 64; ++tt) {
        const int t = tt * 64 + j;
        if (t < len) {
            const int tg = tags[b * TT + t];
            sc += inputs[(size_t)b * TT * NTAG + (size_t)t * NTAG + tg];
            if (t >= 1) {
                const int tp = tags[b * TT + t - 1];
                sc += trans[tp * NTAG + tg];
            }
        }
    }
    #pragma unroll
    for (int m = 32; m >= 1; m >>= 1) sc += __shfl_xor(sc, m);

    // ---------------- E[:,j] = exp(trans[:,j]) into registers --------------
    DECL4(0,1,2,3)   DECL4(4,5,6,7)   DECL4(8,9,10,11)  DECL4(12,13,14,15)
    DECL4(16,17,18,19) DECL4(20,21,22,23) DECL4(24,25,26,27) DECL4(28,29,30,31)
    DECL4(32,33,34,35) DECL4(36,37,38,39) DECL4(40,41,42,43) DECL4(44,45,46,47)
    DECL4(48,49,50,51) DECL4(52,53,54,55) DECL4(56,57,58,59) DECL4(60,61,62,63)

    // Belt-and-suspenders: make the e-values asm-opaque so they cannot be
    // rematerialized from the trans loads inside the loop.
    asm("" : "+v"(e0), "+v"(e1), "+v"(e2), "+v"(e3), "+v"(e4), "+v"(e5),
             "+v"(e6), "+v"(e7), "+v"(e8), "+v"(e9), "+v"(e10), "+v"(e11),
             "+v"(e12), "+v"(e13), "+v"(e14), "+v"(e15));
    asm("" : "+v"(e16), "+v"(e17), "+v"(e18), "+v"(e19), "+v"(e20), "+v"(e21),
             "+v"(e22), "+v"(e23), "+v"(e24), "+v"(e25), "+v"(e26), "+v"(e27),
             "+v"(e28), "+v"(e29), "+v"(e30), "+v"(e31));
    asm("" : "+v"(e32), "+v"(e33), "+v"(e34), "+v"(e35), "+v"(e36), "+v"(e37),
             "+v"(e38), "+v"(e39), "+v"(e40), "+v"(e41), "+v"(e42), "+v"(e43),
             "+v"(e44), "+v"(e45), "+v"(e46), "+v"(e47));
    asm("" : "+v"(e48), "+v"(e49), "+v"(e50), "+v"(e51), "+v"(e52), "+v"(e53),
             "+v"(e54), "+v"(e55), "+v"(e56), "+v"(e57), "+v"(e58), "+v"(e59),
             "+v"(e60), "+v"(e61), "+v"(e62), "+v"(e63));

    // ---------------- forward recurrence ----------------
    const float* emit = inputs + (size_t)b * TT * NTAG;
    float alpha = emit[j];

    // register prefetch ring, distance 3; clamped index is the OOB guard.
    float pre0 = emit[(size_t)min(1, last) * NTAG + j];
    float pre1 = emit[(size_t)min(2, last) * NTAG + j];
    float pre2 = emit[(size_t)min(3, last) * NTAG + j];

    for (int t = 1; t <= last; ++t) {
        const float cur = pre0;
        pre0 = pre1;
        pre1 = pre2;
        pre2 = emit[(size_t)min(t + 3, last) * NTAG + j];

        // C = any uniform shift; lane-0 alpha is within ~20 of the max
        // (spread bounded by emission + transition column spread), so
        // exp stays comfortably in f32 range.
        const float C = BCAST(alpha, 0);

        const float x = __expf(alpha - C);

        // s_j = sum_i x_i * E[i][j] — v_readlane broadcast (SGPR) feeds
        // v_fmac_f32 directly; 4 partial chains shorten the critical path.
        float sA = 0.f, sB = 0.f, sC = 0.f, sD = 0.f;
        FMA4(0,1,2,3)   FMA4(4,5,6,7)   FMA4(8,9,10,11)  FMA4(12,13,14,15)
        FMA4(16,17,18,19) FMA4(20,21,22,23) FMA4(24,25,26,27) FMA4(28,29,30,31)
        FMA4(32,33,34,35) FMA4(36,37,38,39) FMA4(40,41,42,43) FMA4(44,45,46,47)
        FMA4(48,49,50,51) FMA4(52,53,54,55) FMA4(56,57,58,59) FMA4(60,61,62,63)
        const float s = (sA + sB) + (sC + sD);

        alpha = cur + C + __logf(s);
    }

    // final logsumexp over lanes (exact max here — runs once)
    float C2 = alpha;
    #pragma unroll
    for (int m = 32; m >= 1; m >>= 1) C2 = fmaxf(C2, __shfl_xor(C2, m));
    float xs = __expf(alpha - C2);
    #pragma unroll
    for (int m = 32; m >= 1; m >>= 1) xs += __shfl_xor(xs, m);
    const float lognorm = C2 + __logf(xs);

    if (j == 0) out[b] = sc - lognorm;
}

__global__ __launch_bounds__(256) void copy_trans_kernel(
    const float* __restrict__ trans, float* __restrict__ out)
{
    const int k = blockIdx.x * 256 + threadIdx.x;
    if (k < NTAG * NTAG) out[k] = trans[k];
}

extern "C" void kernel_launch(void* const* d_in, const int* in_sizes, int n_in,
                              void* d_out, int out_size, void* d_ws, size_t ws_size,
                              hipStream_t stream) {
    const float* inputs = (const float*)d_in[0];
    const float* trans  = (const float*)d_in[1];
    const int*   tags   = (const int*)d_in[2];
    const int*   lens   = (const int*)d_in[3];
    float* out = (float*)d_out;

    crf_kernel<<<BB, 64, 0, stream>>>(inputs, trans, tags, lens, out);
    copy_trans_kernel<<<(NTAG * NTAG + 255) / 256, 256, 0, stream>>>(trans, out + BB);
}

// Round 10
// 233.142 us; speedup vs baseline: 2.1637x; 1.1667x over previous
//
#include <hip/hip_runtime.h>

#define BB 512
#define TT 512
#define NTAG 64

// Broadcast lane `l`'s value of v to all lanes via v_readlane (SGPR dest).
#define BCAST(v, l) __uint_as_float((unsigned)__builtin_amdgcn_readlane((int)__float_as_uint(v), (l)))

#define DECL4(a,b,c,d) \
    float e##a = __expf(trans[a * NTAG + j]); \
    float e##b = __expf(trans[b * NTAG + j]); \
    float e##c = __expf(trans[c * NTAG + j]); \
    float e##d = __expf(trans[d * NTAG + j]);

#define FMA4(a,b,c,d) \
    sA = fmaf(BCAST(x, a), e##a, sA); \
    sB = fmaf(BCAST(x, b), e##b, sB); \
    sC = fmaf(BCAST(x, c), e##c, sC); \
    sD = fmaf(BCAST(x, d), e##d, sD);

// Emission prefetch: asm global load of row min(row,S) into a named float.
// The compiler's C-level distance-3 ring was (per R8 counters) collapsed to
// depth-1 (s_waitcnt vmcnt(0) per step -> ~700cyc stall/step, 75% of time).
// These asm loads + counted vmcnt(4) waits keep 8 loads in flight.
#define GLOAD(dst, row) \
    asm volatile("global_load_dword %0, %1, off" \
        : "=v"(dst) \
        : "v"(emit + (size_t)((row) < S ? (row) : S) * NTAG + j) \
        : "memory");

// Counted wait: oldest 4 loads (group P) complete; P-regs redefined by the
// asm so the consuming VALU cannot be hoisted above the wait (rule #18).
#define WAIT4(P) \
    asm volatile("s_waitcnt vmcnt(4)" \
        : "+v"(P##0), "+v"(P##1), "+v"(P##2), "+v"(P##3));
#define WAIT0(P) \
    asm volatile("s_waitcnt vmcnt(0)" \
        : "+v"(P##0), "+v"(P##1), "+v"(P##2), "+v"(P##3));

// One recurrence step; cur comes from a prefetched register.
#define STEPC(P) { \
    const float cur = P; \
    const float C = BCAST(alpha, 0); \
    const float x = __expf(alpha - C); \
    float sA = 0.f, sB = 0.f, sC = 0.f, sD = 0.f; \
    FMA4(0,1,2,3)   FMA4(4,5,6,7)   FMA4(8,9,10,11)  FMA4(12,13,14,15) \
    FMA4(16,17,18,19) FMA4(20,21,22,23) FMA4(24,25,26,27) FMA4(28,29,30,31) \
    FMA4(32,33,34,35) FMA4(36,37,38,39) FMA4(40,41,42,43) FMA4(44,45,46,47) \
    FMA4(48,49,50,51) FMA4(52,53,54,55) FMA4(56,57,58,59) FMA4(60,61,62,63) \
    const float s_ = (sA + sB) + (sC + sD); \
    alpha = cur + C + __logf(s_); \
}

// Predicated step for the tail (steps >= S computed on clamped data, discarded).
#define STEPP(P, scur) { \
    const float cur = P; \
    const float C = BCAST(alpha, 0); \
    const float x = __expf(alpha - C); \
    float sA = 0.f, sB = 0.f, sC = 0.f, sD = 0.f; \
    FMA4(0,1,2,3)   FMA4(4,5,6,7)   FMA4(8,9,10,11)  FMA4(12,13,14,15) \
    FMA4(16,17,18,19) FMA4(20,21,22,23) FMA4(24,25,26,27) FMA4(28,29,30,31) \
    FMA4(32,33,34,35) FMA4(36,37,38,39) FMA4(40,41,42,43) FMA4(44,45,46,47) \
    FMA4(48,49,50,51) FMA4(52,53,54,55) FMA4(56,57,58,59) FMA4(60,61,62,63) \
    const float s_ = (sA + sB) + (sC + sD); \
    const float na = cur + C + __logf(s_); \
    alpha = ((scur) < S) ? na : alpha; \
}

// Full group: wait oldest 4, run 4 steps, refill the 4 slots (rows sb+9..sb+12
// = steps sb+8..sb+11, consumed two groups later). vmcnt never drains to 0.
#define GRP(P, sb) \
    WAIT4(P) \
    STEPC(P##0) STEPC(P##1) STEPC(P##2) STEPC(P##3) \
    GLOAD(P##0, (sb) + 9) GLOAD(P##1, (sb) + 10) \
    GLOAD(P##2, (sb) + 11) GLOAD(P##3, (sb) + 12)

// Predicated tail group: drain, consume, no refill.
#define GRPP(P, sb) \
    WAIT0(P) \
    STEPP(P##0, (sb) + 0) STEPP(P##1, (sb) + 1) \
    STEPP(P##2, (sb) + 2) STEPP(P##3, (sb) + 3)

// waves_per_eu(1,1): min AND max 1 wave/EU -> full 512-VGPR budget (proven
// in R8: VGPR_Count 44 -> 132, E genuinely register-resident).
__global__ __attribute__((amdgpu_waves_per_eu(1, 1))) __launch_bounds__(64)
void crf_kernel(
    const float* __restrict__ inputs,   // [B,T,N] f32
    const float* __restrict__ trans,    // [N,N]   f32
    const int*   __restrict__ tags,     // [B,T]   i32
    const int*   __restrict__ lens,     // [B]     i32
    float*       __restrict__ out)      // [B]     f32 (log_likelihood)
{
    const int b = blockIdx.x;
    const int j = threadIdx.x;           // 0..63
    const int len  = lens[b];
    const int S = (len - 1) > 0 ? (len - 1) : 0;   // number of recurrence steps

    // ---------------- sequence score (gathers) ----------------
    float sc = 0.f;
    #pragma unroll
    for (int tt = 0; tt < TT / 64; ++tt) {
        const int t = tt * 64 + j;
        if (t < len) {
            const int tg = tags[b * TT + t];
            sc += inputs[(size_t)b * TT * NTAG + (size_t)t * NTAG + tg];
            if (t >= 1) {
                const int tp = tags[b * TT + t - 1];
                sc += trans[tp * NTAG + tg];
            }
        }
    }
    #pragma unroll
    for (int m = 32; m >= 1; m >>= 1) sc += __shfl_xor(sc, m);

    // ---------------- E[:,j] = exp(trans[:,j]) into registers --------------
    DECL4(0,1,2,3)   DECL4(4,5,6,7)   DECL4(8,9,10,11)  DECL4(12,13,14,15)
    DECL4(16,17,18,19) DECL4(20,21,22,23) DECL4(24,25,26,27) DECL4(28,29,30,31)
    DECL4(32,33,34,35) DECL4(36,37,38,39) DECL4(40,41,42,43) DECL4(44,45,46,47)
    DECL4(48,49,50,51) DECL4(52,53,54,55) DECL4(56,57,58,59) DECL4(60,61,62,63)

    // asm-opaque: cannot be rematerialized from trans loads inside the loop.
    asm("" : "+v"(e0), "+v"(e1), "+v"(e2), "+v"(e3), "+v"(e4), "+v"(e5),
             "+v"(e6), "+v"(e7), "+v"(e8), "+v"(e9), "+v"(e10), "+v"(e11),
             "+v"(e12), "+v"(e13), "+v"(e14), "+v"(e15));
    asm("" : "+v"(e16), "+v"(e17), "+v"(e18), "+v"(e19), "+v"(e20), "+v"(e21),
             "+v"(e22), "+v"(e23), "+v"(e24), "+v"(e25), "+v"(e26), "+v"(e27),
             "+v"(e28), "+v"(e29), "+v"(e30), "+v"(e31));
    asm("" : "+v"(e32), "+v"(e33), "+v"(e34), "+v"(e35), "+v"(e36), "+v"(e37),
             "+v"(e38), "+v"(e39), "+v"(e40), "+v"(e41), "+v"(e42), "+v"(e43),
             "+v"(e44), "+v"(e45), "+v"(e46), "+v"(e47));
    asm("" : "+v"(e48), "+v"(e49), "+v"(e50), "+v"(e51), "+v"(e52), "+v"(e53),
             "+v"(e54), "+v"(e55), "+v"(e56), "+v"(e57), "+v"(e58), "+v"(e59),
             "+v"(e60), "+v"(e61), "+v"(e62), "+v"(e63));

    // ---------------- forward recurrence ----------------
    const float* emit = inputs + (size_t)b * TT * NTAG;
    float alpha = emit[j];            // row 0

    // Drain every prior vmem (preamble gathers, e-loads, alpha) so in-loop
    // vmcnt counting sees ONLY our asm ring loads.
    asm volatile("s_waitcnt vmcnt(0) lgkmcnt(0)" ::: "memory");

    // Prologue: fill the 2-group ring (rows 1..4 -> pA, rows 5..8 -> pB).
    float pA0, pA1, pA2, pA3, pB0, pB1, pB2, pB3;
    GLOAD(pA0, 1) GLOAD(pA1, 2) GLOAD(pA2, 3) GLOAD(pA3, 4)
    GLOAD(pB0, 5) GLOAD(pB1, 6) GLOAD(pB2, 7) GLOAD(pB3, 8)

    int s = 0;
    while (s + 8 <= S) {
        GRP(pA, s)
        GRP(pB, s + 4)
        s += 8;
    }
    if (s < S) { GRPP(pA, s) s += 4; }
    if (s < S) { GRPP(pB, s) s += 4; }

    // drain any leftover ring loads before the epilogue
    asm volatile("s_waitcnt vmcnt(0)" ::: "memory");

    // final logsumexp over lanes (exact max — runs once)
    float C2 = alpha;
    #pragma unroll
    for (int m = 32; m >= 1; m >>= 1) C2 = fmaxf(C2, __shfl_xor(C2, m));
    float xs = __expf(alpha - C2);
    #pragma unroll
    for (int m = 32; m >= 1; m >>= 1) xs += __shfl_xor(xs, m);
    const float lognorm = C2 + __logf(xs);

    if (j == 0) out[b] = sc - lognorm;
}

__global__ __launch_bounds__(256) void copy_trans_kernel(
    const float* __restrict__ trans, float* __restrict__ out)
{
    const int k = blockIdx.x * 256 + threadIdx.x;
    if (k < NTAG * NTAG) out[k] = trans[k];
}

extern "C" void kernel_launch(void* const* d_in, const int* in_sizes, int n_in,
                              void* d_out, int out_size, void* d_ws, size_t ws_size,
                              hipStream_t stream) {
    const float* inputs = (const float*)d_in[0];
    const float* trans  = (const float*)d_in[1];
    const int*   tags   = (const int*)d_in[2];
    const int*   lens   = (const int*)d_in[3];
    float* out = (float*)d_out;

    crf_kernel<<<BB, 64, 0, stream>>>(inputs, trans, tags, lens, out);
    copy_trans_kernel<<<(NTAG * NTAG + 255) / 256, 256, 0, stream>>>(trans, out + BB);
}